// Round 1
// 7958.853 us; speedup vs baseline: 1.2535x; 1.2535x over previous
//
#include <hip/hip_runtime.h>
#include <math.h>

// Problem constants
#define NWG    48       // workgroups = 768/EC ; all co-resident (<=256 CUs)
#define TT     1024     // timesteps per layer
#define BSZ    16       // batch
#define DHH    768      // hidden dim
#define NGG    4        // gates
#define EC     16       // e-chunk per WG
#define LDR    776      // padded K-row length (bf16 elems); 776*2=1552 B, 16B-aligned
#define GP     17       // partial-gates LDS pitch (floats) to avoid bank conflicts
#define KS     192      // K-range per wave (768/4): wave wv accumulates k in [wv*KS, wv*KS+KS)
#define FSTR   32       // flag slot stride in ints (128 B) to avoid line sharing

typedef __attribute__((ext_vector_type(8))) short bf16x8_t;  // 8 bf16 (4 VGPRs) - MFMA A/B frag
typedef __attribute__((ext_vector_type(4))) float f32x4_t;   // MFMA C/D frag

__device__ __forceinline__ unsigned short f2bf(float f) {
  union { float f; unsigned int u; } v; v.f = f;
  return (unsigned short)((v.u + 0x7fffu + ((v.u >> 16) & 1u)) >> 16);  // RNE
}

// Device-coherent (agent-scope, sc1) 16-B A-fragment load: bypasses stale L1/L2,
// served from the coherent point (IC). Relaxed => no fences, loads pipeline freely.
__device__ __forceinline__ bf16x8_t ld_h_frag(const unsigned short* p) {
  union { bf16x8_t v; unsigned long long q[2]; } u;
  u.q[0] = __hip_atomic_load((const unsigned long long*)p,       __ATOMIC_RELAXED, __HIP_MEMORY_SCOPE_AGENT);
  u.q[1] = __hip_atomic_load((const unsigned long long*)(p + 4), __ATOMIC_RELAXED, __HIP_MEMORY_SCOPE_AGENT);
  return u.v;
}

__global__ void lstm_init_ws(int* flags) {
  for (int i = threadIdx.x; i < NWG * FSTR; i += blockDim.x) flags[i] = 0;
}

// Flag-based grid barrier, NO whole-L2 writeback/invalidate:
//  - __syncthreads() emits s_waitcnt vmcnt(0): all of this WG's sc1 (write-through)
//    h-stores are ACKed at the coherent point before the flag is published.
//  - each WG publishes its own epoch slot (plain sc1 store, no RMW contention).
//  - wave 0 polls all 48 slots, one lane per slot, combined with __all.
__device__ __forceinline__ void grid_barrier(int* flags, int wg, int epoch, int lane, int wv) {
  __syncthreads();
  if (wv == 0) {
    if (lane == 0)
      __hip_atomic_store(flags + wg * FSTR, epoch, __ATOMIC_RELAXED, __HIP_MEMORY_SCOPE_AGENT);
    for (;;) {
      int v = (lane < NWG)
            ? __hip_atomic_load(flags + lane * FSTR, __ATOMIC_RELAXED, __HIP_MEMORY_SCOPE_AGENT)
            : epoch;
      if (__all(v >= epoch)) break;
      __builtin_amdgcn_s_sleep(1);
    }
  }
  __syncthreads();
}

__global__ __launch_bounds__(256, 1) void lstm_persistent(
    const float* __restrict__ states,
    const float* __restrict__ Wx0, const float* __restrict__ R0, const float* __restrict__ b0,
    const float* __restrict__ Wx1, const float* __restrict__ R1, const float* __restrict__ b1,
    float* __restrict__ out, int* __restrict__ flags, unsigned short* __restrict__ hbuf)
{
  extern __shared__ unsigned char smem[];
  unsigned short* r_lds    = (unsigned short*)smem;              // [NGG][EC][LDR] bf16, B-operand
  float*          part_lds = (float*)(r_lds + NGG * EC * LDR);   // [4 waves][NGG][BSZ][GP] partial gates
  float*          b_lds    = part_lds + 4 * NGG * BSZ * GP;      // [NGG][EC]

  const int tid  = threadIdx.x;
  const int lane = tid & 63;
  const int wv   = tid >> 6;    // wave id == K-range id
  const int bb   = tid >> 4;    // batch row for elementwise (256 = 16*16)
  const int el   = tid & 15;    // local e
  const int wg   = blockIdx.x;
  const int e0   = wg * EC;
  const int m    = lane & 15;   // MFMA: A-row(batch) for A-frag, B-col(e) for B-frag
  const int q    = lane >> 4;   // MFMA quad

  // ---- init: cell state into a REGISTER (thread<->(b,e) mapping is static),
  //      h0 broadcast (bf16, packed pairs) into hbuf via coherent stores.
  float creg = states[(BSZ + bb) * DHH + e0 + el];
  {
    unsigned hv = f2bf(states[bb * DHH + e0 + el]);
    unsigned pv = (unsigned)__shfl_xor((int)hv, 1, 64);
    if ((el & 1) == 0)
      __hip_atomic_store((unsigned*)(hbuf + bb * DHH + e0 + el), hv | (pv << 16),
                         __ATOMIC_RELAXED, __HIP_MEMORY_SCOPE_AGENT);
  }

  int epoch = 1;
  grid_barrier(flags, wg, epoch, lane, wv);

  for (int layer = 0; layer < 2; ++layer) {
    const float* Wx = layer ? Wx1 : Wx0;
    const float* Rm = layer ? R1  : R0;
    const float* bv = layer ? b1  : b0;

    // Stage R chunk into LDS, transposed to B-frag layout: r_lds[g][n][k=d] = R[g][d][e0+n]
    for (int i = tid; i < NGG * DHH; i += 256) {
      const int g = i / DHH, d = i - g * DHH;
      const float* src = Rm + (g * DHH + d) * DHH + e0;
      #pragma unroll
      for (int n = 0; n < EC; ++n)
        r_lds[(g * EC + n) * LDR + d] = f2bf(src[n]);
    }
    if (tid < NGG * EC) b_lds[tid] = bv[(tid >> 4) * DHH + e0 + (tid & 15)];
    __syncthreads();

    for (int t = 0; t < TT; ++t) {
      const int gs = layer * TT + t;
      const unsigned short* __restrict__ hsrc = hbuf + (gs & 1) * (BSZ * DHH);
      unsigned short* __restrict__ hdst = hbuf + ((gs + 1) & 1) * (BSZ * DHH);

      // Wx loads for this step issued first; their latency is covered by the
      // A-frag IC loads + MFMA phase (first MFMA's counted vmcnt drains them).
      const float* wxp = Wx + ((bb * TT + t) * NGG) * DHH + e0 + el;
      const float wxv0 = wxp[0];
      const float wxv1 = wxp[DHH];
      const float wxv2 = wxp[2 * DHH];
      const float wxv3 = wxp[3 * DHH];

      // MFMA: wave wv accumulates K-range [wv*KS, wv*KS+KS) for ALL 4 gates.
      // A-fragments loaded DIRECTLY from coherent hbuf (no LDS staging, no extra sync).
      {
        const unsigned short* ha = hsrc + m * DHH + wv * KS + q * 8;        // A[m][k]
        const unsigned short* rb = r_lds + m * LDR + wv * KS + q * 8;       // B[k][n=m], gate 0
        f32x4_t ac0 = {0.f, 0.f, 0.f, 0.f};
        f32x4_t ac1 = ac0, ac2 = ac0, ac3 = ac0;
        #pragma unroll
        for (int kk = 0; kk < KS; kk += 32) {
          bf16x8_t av = ld_h_frag(ha + kk);
          ac0 = __builtin_amdgcn_mfma_f32_16x16x32_bf16(av, *(const bf16x8_t*)(rb + kk),               ac0, 0, 0, 0);
          ac1 = __builtin_amdgcn_mfma_f32_16x16x32_bf16(av, *(const bf16x8_t*)(rb + EC * LDR + kk),    ac1, 0, 0, 0);
          ac2 = __builtin_amdgcn_mfma_f32_16x16x32_bf16(av, *(const bf16x8_t*)(rb + 2 * EC * LDR + kk), ac2, 0, 0, 0);
          ac3 = __builtin_amdgcn_mfma_f32_16x16x32_bf16(av, *(const bf16x8_t*)(rb + 3 * EC * LDR + kk), ac3, 0, 0, 0);
        }
        // D layout: row = q*4+r (batch), col = m (e). Partials per wave, reduced in elementwise.
        #pragma unroll
        for (int r = 0; r < 4; ++r) {
          part_lds[((wv * NGG + 0) * BSZ + q * 4 + r) * GP + m] = ac0[r];
          part_lds[((wv * NGG + 1) * BSZ + q * 4 + r) * GP + m] = ac1[r];
          part_lds[((wv * NGG + 2) * BSZ + q * 4 + r) * GP + m] = ac2[r];
          part_lds[((wv * NGG + 3) * BSZ + q * 4 + r) * GP + m] = ac3[r];
        }
      }
      __syncthreads();

      // Elementwise LSTM update: one (b, e) per thread; reduce 4 K-partials per gate.
      {
        float gi = wxv0 + b_lds[0 * EC + el];
        float gf = wxv1 + b_lds[1 * EC + el];
        float gz = wxv2 + b_lds[2 * EC + el];
        float go = wxv3 + b_lds[3 * EC + el];
        #pragma unroll
        for (int w = 0; w < 4; ++w) {
          gi += part_lds[((w * NGG + 0) * BSZ + bb) * GP + el];
          gf += part_lds[((w * NGG + 1) * BSZ + bb) * GP + el];
          gz += part_lds[((w * NGG + 2) * BSZ + bb) * GP + el];
          go += part_lds[((w * NGG + 3) * BSZ + bb) * GP + el];
        }
        const float iv = 1.f / (1.f + __expf(-gi));
        const float fv = 1.f / (1.f + __expf(-gf));
        const float zv = tanhf(gz);
        const float ov = 1.f / (1.f + __expf(-go));
        const float cnew = fv * creg + iv * zv;
        const float hnew = ov * tanhf(cnew);
        creg = cnew;

        // h -> hbuf via coherent packed-pair stores (write-through to IC)
        unsigned hv = f2bf(hnew);
        unsigned pv = (unsigned)__shfl_xor((int)hv, 1, 64);
        if ((el & 1) == 0)
          __hip_atomic_store((unsigned*)(hdst + bb * DHH + e0 + el), hv | (pv << 16),
                             __ATOMIC_RELAXED, __HIP_MEMORY_SCOPE_AGENT);

        if (layer == 1) {
          out[((t * 2 + 0) * BSZ + bb) * DHH + e0 + el] = hnew;
          out[((t * 2 + 1) * BSZ + bb) * DHH + e0 + el] = cnew;
          if (t == TT - 1) {
            const int HS = TT * 2 * BSZ * DHH;   // 25165824
            out[HS + (0 * BSZ + bb) * DHH + e0 + el] = hnew;               // last_h
            out[HS + (1 * BSZ + bb) * DHH + e0 + el] = cnew;
            out[HS + 2 * BSZ * DHH + (0 * BSZ + bb) * DHH + e0 + el] = hnew; // out (duplicate)
            out[HS + 2 * BSZ * DHH + (1 * BSZ + bb) * DHH + e0 + el] = cnew;
          }
        }
      }

      // Inter-WG barrier (skip after the very last step)
      if (gs != 2 * TT - 1) {
        ++epoch;
        grid_barrier(flags, wg, epoch, lane, wv);
      }
    }
  }
}

extern "C" void kernel_launch(void* const* d_in, const int* in_sizes, int n_in,
                              void* d_out, int out_size, void* d_ws, size_t ws_size,
                              hipStream_t stream) {
  const float* states = (const float*)d_in[0];
  const float* Wx0    = (const float*)d_in[1];
  const float* R0     = (const float*)d_in[2];
  const float* b0     = (const float*)d_in[3];
  const float* Wx1    = (const float*)d_in[4];
  const float* R1     = (const float*)d_in[5];
  const float* b1     = (const float*)d_in[6];
  float* out = (float*)d_out;

  int* flags = (int*)d_ws;
  unsigned short* hbuf = (unsigned short*)((char*)d_ws + 8192);  // [2][16*768] bf16

  const int smem_bytes = (NGG * EC * LDR) * 2 +
                         (4 * NGG * BSZ * GP + NGG * EC) * 4;    // 116992 B

  static bool attr_set = false;  // idempotent host-side attribute; same work every call
  if (!attr_set) {
    hipFuncSetAttribute((const void*)lstm_persistent,
                        hipFuncAttributeMaxDynamicSharedMemorySize, smem_bytes);
    attr_set = true;
  }

  lstm_init_ws<<<dim3(1), dim3(256), 0, stream>>>(flags);
  lstm_persistent<<<dim3(NWG), dim3(256), smem_bytes, stream>>>(
      states, Wx0, R0, b0, Wx1, R1, b1, out, flags, hbuf);
}

// Round 2
// 7112.449 us; speedup vs baseline: 1.4027x; 1.1190x over previous
//
#include <hip/hip_runtime.h>
#include <math.h>

// Problem constants
#define NWG    48       // workgroups = 768/EC ; all co-resident (<=256 CUs)
#define TT     1024     // timesteps per layer
#define BSZ    16       // batch
#define DHH    768      // hidden dim
#define NGG    4        // gates
#define EC     16       // e-chunk per WG
#define LDR    776      // padded K-row length (bf16 elems); 776*2=1552 B, 16B-aligned
#define GP     17       // partial-gates LDS pitch (floats) to avoid bank conflicts
#define KS     192      // K-range per wave (768/4)
#define FSTR   32       // flag slot stride in ints (128 B)

typedef __attribute__((ext_vector_type(8))) short bf16x8_t;  // 8 bf16 (4 VGPRs)
typedef __attribute__((ext_vector_type(4))) float f32x4_t;   // MFMA C/D frag

#define MF(a,b,c) __builtin_amdgcn_mfma_f32_16x16x32_bf16((a),(b),(c),0,0,0)

__device__ __forceinline__ unsigned short f2bf(float f) {
  union { float f; unsigned int u; } v; v.f = f;
  return (unsigned short)((v.u + 0x7fffu + ((v.u >> 16) & 1u)) >> 16);  // RNE
}
__device__ __forceinline__ float sigm(float x)      { return 1.f / (1.f + __expf(-x)); }
__device__ __forceinline__ float tanh_fast(float x) { return 1.f - 2.f / (__expf(2.f * x) + 1.f); }

// ---- inline-asm memory helpers ----
// Agent-coherent (sc1) 16B load: bypasses L1/L2, served at the coherent point (IC).
__device__ __forceinline__ void ldg_a16_sc(bf16x8_t& d, const unsigned short* p) {
  asm volatile("global_load_dwordx4 %0, %1, off sc1" : "=v"(d) : "v"(p));
}
// Normal cached load (Wx prefetch; data consumed only after a later vmcnt(0)).
__device__ __forceinline__ void ldg_f32(float& d, const float* p) {
  asm volatile("global_load_dword %0, %1, off" : "=v"(d) : "v"(p));
}
// Agent-coherent store (write-through to IC).
__device__ __forceinline__ void stg_u32_sc(unsigned* p, unsigned v) {
  asm volatile("global_store_dword %0, %1, off sc1" :: "v"(p), "v"(v) : "memory");
}
__device__ __forceinline__ void wait_vm0() {            // drain all vmem (loads)
  asm volatile("s_waitcnt vmcnt(0)" ::: "memory");
}
__device__ __forceinline__ void wait_lgkm_barrier() {   // LDS-only barrier (no vmem drain!)
  asm volatile("s_waitcnt lgkmcnt(0)\ns_barrier" ::: "memory");
}
__device__ __forceinline__ void wait_vm0_barrier() {    // full drain + barrier (pre-flag)
  asm volatile("s_waitcnt vmcnt(0) lgkmcnt(0)\ns_barrier" ::: "memory");
}

__global__ void lstm_init_ws(int* flags) {
  for (int i = threadIdx.x; i < NWG * FSTR; i += blockDim.x) flags[i] = 0;
}

// All waves poll all 48 flags (one lane per flag), SKIPPING our own slot:
// our own h-stores were vmcnt(0)-drained to the coherent point before our flag
// store, so our own data is visible to our own sc1 loads without seeing the flag.
__device__ __forceinline__ void poll_flags(const int* fp, bool self_or_oob, int epoch) {
  for (;;) {
    int v = self_or_oob ? epoch
                        : __hip_atomic_load(fp, __ATOMIC_RELAXED, __HIP_MEMORY_SCOPE_AGENT);
    if (__all(v >= epoch)) break;
  }
}

__global__ __launch_bounds__(256, 1) void lstm_persistent(
    const float* __restrict__ states,
    const float* __restrict__ Wx0, const float* __restrict__ R0, const float* __restrict__ b0,
    const float* __restrict__ Wx1, const float* __restrict__ R1, const float* __restrict__ b1,
    float* __restrict__ out, int* __restrict__ flags, unsigned short* __restrict__ hbuf)
{
  extern __shared__ unsigned char smem[];
  unsigned short* r_lds    = (unsigned short*)smem;              // [NGG][EC][LDR] bf16 (staging for B-frags)
  float*          part_lds = (float*)(r_lds + NGG * EC * LDR);   // [4 waves][NGG][BSZ][GP] partial gates

  const int tid  = threadIdx.x;
  const int lane = tid & 63;
  const int wv   = tid >> 6;    // wave id == K-range id
  const int bb   = tid >> 4;    // batch row for elementwise (256 = 16*16)
  const int el   = tid & 15;    // local e
  const int wg   = blockIdx.x;
  const int e0   = wg * EC;
  const int m    = lane & 15;   // MFMA: A-row(batch) / B-col(e)
  const int q    = lane >> 4;   // MFMA quad

  const int aofs = m * DHH + wv * KS + q * 8;          // A-frag offset into h buffer
  const int hofs = bb * DHH + e0 + el;                 // h store/broadcast offset
  const int* fp  = flags + (lane < NWG ? lane : 0) * FSTR;
  const bool self_skip = (lane >= NWG) || (lane == wg);

  // ---- init: cell state in a register; h0 broadcast (bf16 packed pairs) to IC
  float creg = states[(BSZ + bb) * DHH + e0 + el];
  {
    unsigned hv = f2bf(states[bb * DHH + e0 + el]);
    unsigned pv = (unsigned)__shfl_xor((int)hv, 1, 64);
    if ((el & 1) == 0)
      stg_u32_sc((unsigned*)(hbuf + hofs), hv | (pv << 16));
  }

  int epoch = 1;
  wait_vm0_barrier();
  if (tid == 0)
    __hip_atomic_store(flags + wg * FSTR, epoch, __ATOMIC_RELAXED, __HIP_MEMORY_SCOPE_AGENT);
  // prefetch Wx for gs=0 (covered by vmcnt(0)s inside the poll)
  float pw0, pw1, pw2, pw3;
  {
    const float* wxp = Wx0 + ((bb * TT + 0) * NGG) * DHH + e0 + el;
    ldg_f32(pw0, wxp); ldg_f32(pw1, wxp + DHH);
    ldg_f32(pw2, wxp + 2 * DHH); ldg_f32(pw3, wxp + 3 * DHH);
  }
  poll_flags(fp, self_skip, epoch);
  __builtin_amdgcn_sched_barrier(0);

  int oofs = bb * DHH + e0 + el;   // running out offset (layer 1)

  for (int layer = 0; layer < 2; ++layer) {
    const float* Wx = layer ? Wx1 : Wx0;
    const float* Rm = layer ? R1  : R0;
    const float* bv = layer ? b1  : b0;

    // Stage R chunk into LDS, transposed to B-frag layout: r_lds[g][n][k=d] = R[g][d][e0+n]
    for (int i = tid; i < NGG * DHH; i += 256) {
      const int g = i / DHH, d = i - g * DHH;
      const float* src = Rm + (g * DHH + d) * DHH + e0;
      #pragma unroll
      for (int n = 0; n < EC; ++n)
        r_lds[(g * EC + n) * LDR + d] = f2bf(src[n]);
    }
    __syncthreads();

    // One-time per layer: all 24 B-fragments (4 gates x 6 k-tiles) -> registers.
    // Loop-invariant across all 1024 steps: removes every steady-state B ds_read.
    bf16x8_t B00,B01,B02,B03,B04,B05, B10,B11,B12,B13,B14,B15,
             B20,B21,B22,B23,B24,B25, B30,B31,B32,B33,B34,B35;
    {
      const unsigned short* rb = r_lds + m * LDR + wv * KS + q * 8;
      B00 = *(const bf16x8_t*)(rb + 0*EC*LDR +   0); B01 = *(const bf16x8_t*)(rb + 0*EC*LDR +  32);
      B02 = *(const bf16x8_t*)(rb + 0*EC*LDR +  64); B03 = *(const bf16x8_t*)(rb + 0*EC*LDR +  96);
      B04 = *(const bf16x8_t*)(rb + 0*EC*LDR + 128); B05 = *(const bf16x8_t*)(rb + 0*EC*LDR + 160);
      B10 = *(const bf16x8_t*)(rb + 1*EC*LDR +   0); B11 = *(const bf16x8_t*)(rb + 1*EC*LDR +  32);
      B12 = *(const bf16x8_t*)(rb + 1*EC*LDR +  64); B13 = *(const bf16x8_t*)(rb + 1*EC*LDR +  96);
      B14 = *(const bf16x8_t*)(rb + 1*EC*LDR + 128); B15 = *(const bf16x8_t*)(rb + 1*EC*LDR + 160);
      B20 = *(const bf16x8_t*)(rb + 2*EC*LDR +   0); B21 = *(const bf16x8_t*)(rb + 2*EC*LDR +  32);
      B22 = *(const bf16x8_t*)(rb + 2*EC*LDR +  64); B23 = *(const bf16x8_t*)(rb + 2*EC*LDR +  96);
      B24 = *(const bf16x8_t*)(rb + 2*EC*LDR + 128); B25 = *(const bf16x8_t*)(rb + 2*EC*LDR + 160);
      B30 = *(const bf16x8_t*)(rb + 3*EC*LDR +   0); B31 = *(const bf16x8_t*)(rb + 3*EC*LDR +  32);
      B32 = *(const bf16x8_t*)(rb + 3*EC*LDR +  64); B33 = *(const bf16x8_t*)(rb + 3*EC*LDR +  96);
      B34 = *(const bf16x8_t*)(rb + 3*EC*LDR + 128); B35 = *(const bf16x8_t*)(rb + 3*EC*LDR + 160);
    }
    // biases -> registers (per-thread (g, el) values)
    const float bi_ = bv[0 * DHH + e0 + el];
    const float bf_ = bv[1 * DHH + e0 + el];
    const float bz_ = bv[2 * DHH + e0 + el];
    const float bo_ = bv[3 * DHH + e0 + el];

    for (int t = 0; t < TT; ++t) {
      const int gs = layer * TT + t;
      const unsigned short* __restrict__ hsrc = hbuf + (gs & 1) * (BSZ * DHH);
      unsigned short* __restrict__ hdst = hbuf + ((gs + 1) & 1) * (BSZ * DHH);

      // current-step Wx from prefetch regs (data covered by previous step's vmcnt(0))
      const float qw0 = pw0, qw1 = pw1, qw2 = pw2, qw3 = pw3;

      // issue A-frag loads (agent-coherent, batch of 6)
      bf16x8_t av0, av1, av2, av3, av4, av5;
      {
        const unsigned short* ha = hsrc + aofs;
        ldg_a16_sc(av0, ha +   0); ldg_a16_sc(av1, ha +  32);
        ldg_a16_sc(av2, ha +  64); ldg_a16_sc(av3, ha +  96);
        ldg_a16_sc(av4, ha + 128); ldg_a16_sc(av5, ha + 160);
      }
      // issue next-step Wx prefetch (hidden under the same vmcnt wait)
      if (gs + 1 < 2 * TT) {
        const int g2 = gs + 1, l2 = g2 >> 10, t2 = g2 & (TT - 1);
        const float* wxp = (l2 ? Wx1 : Wx0) + ((bb * TT + t2) * NGG) * DHH + e0 + el;
        ldg_f32(pw0, wxp); ldg_f32(pw1, wxp + DHH);
        ldg_f32(pw2, wxp + 2 * DHH); ldg_f32(pw3, wxp + 3 * DHH);
      }
      wait_vm0();
      __builtin_amdgcn_sched_barrier(0);   // rule #18: MFMA must not hoist above the wait

      // 24 MFMAs, all operands in registers (4 independent acc chains of 6)
      f32x4_t ac0 = {0.f,0.f,0.f,0.f}, ac1 = ac0, ac2 = ac0, ac3 = ac0;
      ac0 = MF(av0,B00,ac0); ac1 = MF(av0,B10,ac1); ac2 = MF(av0,B20,ac2); ac3 = MF(av0,B30,ac3);
      ac0 = MF(av1,B01,ac0); ac1 = MF(av1,B11,ac1); ac2 = MF(av1,B21,ac2); ac3 = MF(av1,B31,ac3);
      ac0 = MF(av2,B02,ac0); ac1 = MF(av2,B12,ac1); ac2 = MF(av2,B22,ac2); ac3 = MF(av2,B32,ac3);
      ac0 = MF(av3,B03,ac0); ac1 = MF(av3,B13,ac1); ac2 = MF(av3,B23,ac2); ac3 = MF(av3,B33,ac3);
      ac0 = MF(av4,B04,ac0); ac1 = MF(av4,B14,ac1); ac2 = MF(av4,B24,ac2); ac3 = MF(av4,B34,ac3);
      ac0 = MF(av5,B05,ac0); ac1 = MF(av5,B15,ac1); ac2 = MF(av5,B25,ac2); ac3 = MF(av5,B35,ac3);

      // partials -> LDS; D layout: row = q*4+r (batch), col = m (e)
      #pragma unroll
      for (int r = 0; r < 4; ++r) {
        part_lds[((wv * NGG + 0) * BSZ + q * 4 + r) * GP + m] = ac0[r];
        part_lds[((wv * NGG + 1) * BSZ + q * 4 + r) * GP + m] = ac1[r];
        part_lds[((wv * NGG + 2) * BSZ + q * 4 + r) * GP + m] = ac2[r];
        part_lds[((wv * NGG + 3) * BSZ + q * 4 + r) * GP + m] = ac3[r];
      }
      wait_lgkm_barrier();   // LDS-only barrier: prefetch loads stay in flight

      // Elementwise LSTM update: one (b, e) per thread; reduce 4 K-partials/gate
      {
        float gi = qw0 + bi_, gf = qw1 + bf_, gz = qw2 + bz_, go = qw3 + bo_;
        #pragma unroll
        for (int w = 0; w < 4; ++w) {
          gi += part_lds[((w * NGG + 0) * BSZ + bb) * GP + el];
          gf += part_lds[((w * NGG + 1) * BSZ + bb) * GP + el];
          gz += part_lds[((w * NGG + 2) * BSZ + bb) * GP + el];
          go += part_lds[((w * NGG + 3) * BSZ + bb) * GP + el];
        }
        const float iv = sigm(gi), fv = sigm(gf), zv = tanh_fast(gz), ov = sigm(go);
        const float cnew = fv * creg + iv * zv;
        const float hnew = ov * tanh_fast(cnew);
        creg = cnew;

        unsigned hv = f2bf(hnew);
        unsigned pv = (unsigned)__shfl_xor((int)hv, 1, 64);
        if ((el & 1) == 0)
          stg_u32_sc((unsigned*)(hdst + hofs), hv | (pv << 16));

        if (layer == 1) {
          out[oofs] = hnew;
          out[oofs + BSZ * DHH] = cnew;
          if (t == TT - 1) {
            const int HS = TT * 2 * BSZ * DHH;   // 25165824
            out[HS + bb * DHH + e0 + el] = hnew;                         // last_h
            out[HS + BSZ * DHH + bb * DHH + e0 + el] = cnew;
            out[HS + 2 * BSZ * DHH + bb * DHH + e0 + el] = hnew;         // out (duplicate)
            out[HS + 3 * BSZ * DHH + bb * DHH + e0 + el] = cnew;
          }
          oofs += 2 * BSZ * DHH;
        }
      }

      // publish + poll (skip after the very last step)
      if (gs != 2 * TT - 1) {
        ++epoch;
        wait_vm0_barrier();   // h stores (sc1) + out stores ACKed; all waves synced
        if (tid == 0)
          __hip_atomic_store(flags + wg * FSTR, epoch, __ATOMIC_RELAXED, __HIP_MEMORY_SCOPE_AGENT);
        poll_flags(fp, self_skip, epoch);
        __builtin_amdgcn_sched_barrier(0);
      }
    }
  }
}

extern "C" void kernel_launch(void* const* d_in, const int* in_sizes, int n_in,
                              void* d_out, int out_size, void* d_ws, size_t ws_size,
                              hipStream_t stream) {
  const float* states = (const float*)d_in[0];
  const float* Wx0    = (const float*)d_in[1];
  const float* R0     = (const float*)d_in[2];
  const float* b0     = (const float*)d_in[3];
  const float* Wx1    = (const float*)d_in[4];
  const float* R1     = (const float*)d_in[5];
  const float* b1     = (const float*)d_in[6];
  float* out = (float*)d_out;

  int* flags = (int*)d_ws;
  unsigned short* hbuf = (unsigned short*)((char*)d_ws + 8192);  // [2][16*768] bf16

  const int smem_bytes = (NGG * EC * LDR) * 2 + (4 * NGG * BSZ * GP) * 4;  // 116736 B

  static bool attr_set = false;  // idempotent host-side attribute; same work every call
  if (!attr_set) {
    hipFuncSetAttribute((const void*)lstm_persistent,
                        hipFuncAttributeMaxDynamicSharedMemorySize, smem_bytes);
    attr_set = true;
  }

  lstm_init_ws<<<dim3(1), dim3(256), 0, stream>>>(flags);
  lstm_persistent<<<dim3(NWG), dim3(256), smem_bytes, stream>>>(
      states, Wx0, R0, b0, Wx1, R1, b1, out, flags, hbuf);
}